// Round 15
// baseline (257.735 us; speedup 1.0000x reference)
//
#include <hip/hip_runtime.h>
#include <math.h>

// PoseMLP, transposed split-f16 MFMA, R15: cross the occupancy tier.
// R14 (weights->LDS) = 94us, occupancy still ~19% (2 waves/SIMD: 128 VGPR +
// ~128 hidden AGPR = 256 unified -> tier 512/256=2). This round removes the
// last big persistent reg block (bias2v, 32 regs) by staging b2 into LDS
// (pre-permuted by the C/D row map; C-init via 4 broadcast ds_read_b128),
// and declares __launch_bounds__(256,3) so the allocator targets <=170
// unified regs -> 3 waves/SIMD tier.
// Falsifier: if it spills (scratch traffic, dur>110), revert bounds to 2.
//
// Split math (verified R5..R14, absmax 0.0039 = fp32 class):
//   a = hi + lo*2^-12; hi = RTZ_f16(a), lo = RTZ_f16((a-hi)*4096).
//   res = acc_hh + (acc_hl + acc_lh)*2^-12  (lo*lo dropped ~2^-24).
// L1 bias folded into k=7 slot (B k7 = 1.0 g0 lanes, A k7 = split(b1)).
//
// v_mfma_f32_32x32x16_f16 layouts (verified R5..R14):
//   A: row=lane&31, k=8*(lane>>5)+j ; B: col=lane&31, k=8*(lane>>5)+j
//   D: col=lane&31, row=(i&3)+8*(i>>2)+4*(lane>>5)
// sigma relabeling: packed D word (ct,m) == B-frag kb=2ct+(m>>2), w=m&3;
// consumer weight columns pre-permuted by sigma_inv at LDS-stage time.
//
// LDS: 28 weight frag slots (half8, index p*64+lane) + b2 C-init table
// (64 floats: [(g*2+ct)*16 + i] = b2[ct*32 + crow(i,g)]).

typedef _Float16 half8  __attribute__((ext_vector_type(8)));
typedef __fp16   fp16x2 __attribute__((ext_vector_type(2)));
typedef float    floatx16 __attribute__((ext_vector_type(16)));
typedef unsigned int uint2v __attribute__((ext_vector_type(2)));

#define MFMA32(a, b, c) __builtin_amdgcn_mfma_f32_32x32x16_f16((a), (b), (c), 0, 0, 0)
#define LO_SCALE 2.44140625e-4f  /* 2^-12 */

union PairU { fp16x2 h; unsigned int u; };
union FragU { unsigned int w[4]; half8 h; };

static __device__ inline void split_pack2(float v0, float v1,
                                          unsigned int& hw, unsigned int& lw) {
    PairU hp, lp;
    hp.h = __builtin_amdgcn_cvt_pkrtz(v0, v1);          // 1 instr, RTZ
    float f0 = (float)hp.h[0], f1 = (float)hp.h[1];
    lp.h = __builtin_amdgcn_cvt_pkrtz((v0 - f0) * 4096.0f,
                                      (v1 - f1) * 4096.0f);
    hw = hp.u; lw = lp.u;
}

// B k-slot -> producer's natural output-neuron position (see R10 header).
static __device__ inline int sigma_inv(int k) {
    int ci = k >> 5, r = k & 31;
    int m  = 4 * ((r >> 4) & 1) + ((r >> 1) & 3);
    int i  = 2 * m + (r & 1);
    int gD = (r >> 3) & 1;
    return 32 * ci + (i & 3) + 8 * (i >> 2) + 4 * gD;
}

// 2x2 half-block transpose (quat epilogue only)
static __device__ inline void swap32(unsigned int a, unsigned int b,
                                     unsigned int& lo, unsigned int& hi) {
    uint2v r = __builtin_amdgcn_permlane32_swap(a, b, false, false);
    lo = r[0]; hi = r[1];
}

__global__ __launch_bounds__(256, 3) void pose_mlp_mfma_o(
    const float* __restrict__ x,
    const float* __restrict__ W1, const float* __restrict__ b1,
    const float* __restrict__ W2, const float* __restrict__ b2,
    const float* __restrict__ W3, const float* __restrict__ b3,
    float* __restrict__ out, int nrows)
{
    const int tid  = threadIdx.x;
    const int lane = tid & 63;
    const int wv   = tid >> 6;
    const int g    = lane >> 5;   // lane half (k-group / row-group)
    const int n5   = lane & 31;   // neuron row (A) / batch col (B/D)

    __shared__ half8 ldsW[28 * 64];   // 28 KB pre-split weight fragments
    __shared__ float b2lds[64];       // b2 C-init table, crow-permuted

    // ---- stage b2 table (threads 0..63) ----
    if (tid < 64) {
        const int gg = tid >> 5, ct = (tid >> 4) & 1, i = tid & 15;
        b2lds[tid] = b2[ct * 32 + (i & 3) + 8 * (i >> 2) + 4 * gg];
    }

    // ---- stage weight fragments (4 waves cooperatively, own lane each) ----
    for (int p = wv; p < 14; p += 4) {
        FragU H, L;
        if (p < 2) {                       // W1 pair, ct = p
            const int ct = p;
#pragma unroll
            for (int m = 0; m < 4; ++m) {
                int k0 = 2 * m, k1 = 2 * m + 1;
                float a0 = (g == 0) ? W1[(ct * 32 + n5) * 7 + k0] : 0.0f;
                float a1 = (g == 0) ? ((k1 < 7) ? W1[(ct * 32 + n5) * 7 + k1]
                                                : b1[ct * 32 + n5]) : 0.0f;
                split_pack2(a0, a1, H.w[m], L.w[m]);
            }
        } else if (p < 10) {               // W2 pair, q = p-2 -> (ct, kb)
            const int q = p - 2, ct = q >> 2, kb = q & 3;
            const float* wrow = W2 + (ct * 32 + n5) * 64;
#pragma unroll
            for (int m = 0; m < 4; ++m) {
                int k0 = kb * 16 + g * 8 + 2 * m;
                split_pack2(wrow[sigma_inv(k0)], wrow[sigma_inv(k0 + 1)],
                            H.w[m], L.w[m]);
            }
        } else {                           // W3 pair, kb = p-10
            const int kb = p - 10;
            const bool nv = (n5 < 7);
#pragma unroll
            for (int m = 0; m < 4; ++m) {
                int k0 = kb * 16 + g * 8 + 2 * m;
                float a0 = nv ? W3[n5 * 64 + sigma_inv(k0)]     : 0.0f;
                float a1 = nv ? W3[n5 * 64 + sigma_inv(k0 + 1)] : 0.0f;
                split_pack2(a0, a1, H.w[m], L.w[m]);
            }
        }
        ldsW[p * 64 + lane]        = H.h;
        ldsW[(14 + p) * 64 + lane] = L.h;
    }

    // loop-invariant accumulator C operand (zeros)
    floatx16 zero16;
#pragma unroll
    for (int i = 0; i < 16; ++i) zero16[i] = 0.0f;
    float b3t[4];
#pragma unroll
    for (int i = 0; i < 4; ++i)
        b3t[i] = g ? ((i < 3) ? b3[4 + i] : 0.0f) : b3[i];
    const float x7 = (g == 0) ? 1.0f : 0.0f;

    __syncthreads();   // weights + b2 table visible to all waves

    // ---------------- main loop: ITERS x 128 rows/block ----------------
    const int ITERS = 16;
    const int blk0 = blockIdx.x * (ITERS * 128);

    float xv[7] = {0.f,0.f,0.f,0.f,0.f,0.f,0.f};  // stays 0 in g1 lanes
    {
        int r = blk0 + wv * 32 + n5;
        if (g == 0 && r < nrows) {
            const float* xr = x + (size_t)r * 7;
#pragma unroll
            for (int j = 0; j < 7; ++j) xv[j] = xr[j];
        }
    }

    for (int it = 0; it < ITERS; ++it) {
        const int r0 = blk0 + it * 128 + wv * 32;

        // ---- X B-frag ----
        FragU xH, xL;
        split_pack2(xv[0], xv[1], xH.w[0], xL.w[0]);
        split_pack2(xv[2], xv[3], xH.w[1], xL.w[1]);
        split_pack2(xv[4], xv[5], xH.w[2], xL.w[2]);
        split_pack2(xv[6], x7,    xH.w[3], xL.w[3]);

        if (it < ITERS - 1) {
            int r = r0 + 128 + n5;
            if (g == 0 && r < nrows) {
                const float* xr = x + (size_t)r * 7;
#pragma unroll
                for (int j = 0; j < 7; ++j) xv[j] = xr[j];
            }
        }

        // ---- Layer 1: h1^T ; pack DIRECTLY into L2 B-frags (sigma) ----
        FragU AH[4], AL[4];
#pragma unroll
        for (int ct = 0; ct < 2; ++ct) {
            half8 wh = ldsW[ct * 64 + lane];
            half8 wl = ldsW[(14 + ct) * 64 + lane];
            floatx16 ah = MFMA32(wh, xH.h, zero16);
            floatx16 al = MFMA32(wh, xL.h, zero16);
            al = MFMA32(wl, xH.h, al);
#pragma unroll
            for (int m = 0; m < 8; ++m) {
                float v0 = fmaxf(fmaf(al[2*m],   LO_SCALE, ah[2*m]),   0.0f);
                float v1 = fmaxf(fmaf(al[2*m+1], LO_SCALE, ah[2*m+1]), 0.0f);
                const int kb = 2 * ct + (m >> 2), w = m & 3;
                split_pack2(v0, v1, AH[kb].w[w], AL[kb].w[w]);
            }
        }

        // ---- Layer 2: h2^T ; pack into L3 B-frags (sigma) ----
        FragU BH[4], BL[4];
#pragma unroll
        for (int ct = 0; ct < 2; ++ct) {
            // bias C-init from LDS (broadcast reads, transient regs)
            floatx16 cinit = *(const floatx16*)&b2lds[(g * 2 + ct) * 16];
            floatx16 ch, cl;
#pragma unroll
            for (int kb = 0; kb < 4; ++kb) {
                half8 wh = ldsW[(2 + ct * 4 + kb) * 64 + lane];
                half8 wl = ldsW[(16 + ct * 4 + kb) * 64 + lane];
                if (kb == 0) {
                    ch = MFMA32(wh, AH[0].h, cinit);
                    cl = MFMA32(wh, AL[0].h, zero16);
                    cl = MFMA32(wl, AH[0].h, cl);
                } else {
                    ch = MFMA32(wh, AH[kb].h, ch);
                    cl = MFMA32(wh, AL[kb].h, cl);
                    cl = MFMA32(wl, AH[kb].h, cl);
                }
            }
#pragma unroll
            for (int m = 0; m < 8; ++m) {
                float v0 = fmaxf(fmaf(cl[2*m],   LO_SCALE, ch[2*m]),   0.0f);
                float v1 = fmaxf(fmaf(cl[2*m+1], LO_SCALE, ch[2*m+1]), 0.0f);
                const int kb = 2 * ct + (m >> 2), w = m & 3;
                split_pack2(v0, v1, BH[kb].w[w], BL[kb].w[w]);
            }
        }

        // ---- Layer 3: o^T rows 0..6 + quat epilogue ----
        {
            floatx16 oh, ol;
#pragma unroll
            for (int kb = 0; kb < 4; ++kb) {
                half8 wh = ldsW[(10 + kb) * 64 + lane];
                half8 wl = ldsW[(24 + kb) * 64 + lane];
                if (kb == 0) {
                    oh = MFMA32(wh, BH[0].h, zero16);
                    ol = MFMA32(wh, BL[0].h, zero16);
                    ol = MFMA32(wl, BH[0].h, ol);
                } else {
                    oh = MFMA32(wh, BH[kb].h, oh);
                    ol = MFMA32(wh, BL[kb].h, ol);
                    ol = MFMA32(wl, BH[kb].h, ol);
                }
            }
            float c0 = fmaf(ol[0], LO_SCALE, oh[0]) + b3t[0];
            float c1 = fmaf(ol[1], LO_SCALE, oh[1]) + b3t[1];
            float c2 = fmaf(ol[2], LO_SCALE, oh[2]) + b3t[2];
            float c3 = fmaf(ol[3], LO_SCALE, oh[3]) + b3t[3];

            float p = g ? fmaf(c2, c2, fmaf(c1, c1, c0 * c0)) : c3 * c3;
            unsigned int plo, phi;
            swap32(__float_as_uint(p), __float_as_uint(p), plo, phi);
            float other = __uint_as_float(g ? plo : phi);
            float s = p + other;
            float rn = 1.0f / sqrtf(s);

            int r = r0 + n5;
            if (r < nrows) {
                float* orow = out + (size_t)r * 7;
                if (g == 0) {
                    orow[0] = c0; orow[1] = c1; orow[2] = c2; orow[3] = c3 * rn;
                } else {
                    orow[4] = c0 * rn; orow[5] = c1 * rn; orow[6] = c2 * rn;
                }
            }
        }
    }
}

extern "C" void kernel_launch(void* const* d_in, const int* in_sizes, int n_in,
                              void* d_out, int out_size, void* d_ws, size_t ws_size,
                              hipStream_t stream)
{
    const float* x  = (const float*)d_in[0];
    const float* W1 = (const float*)d_in[1];
    const float* b1 = (const float*)d_in[2];
    const float* W2 = (const float*)d_in[3];
    const float* b2 = (const float*)d_in[4];
    const float* W3 = (const float*)d_in[5];
    const float* b3 = (const float*)d_in[6];
    float* out = (float*)d_out;

    const int nrows = in_sizes[0] / 7;
    const int rows_per_block = 16 * 128;  // ITERS * 128
    const int grid = (nrows + rows_per_block - 1) / rows_per_block;
    pose_mlp_mfma_o<<<grid, 256, 0, stream>>>(x, W1, b1, W2, b2, W3, b3, out, nrows);
}

// Round 16
// 102.784 us; speedup vs baseline: 2.5075x; 2.5075x over previous
//
#include <hip/hip_runtime.h>
#include <math.h>

// PoseMLP, transposed split-f16 MFMA, R16:
// R15 post-mortem: launch_bounds(256,3) forced VGPR=84 -> massive scratch
// spill (FETCH 29k->548k KB, 258us). Unified reg demand is ~250+; the
// 3-wave tier is unreachable. Revert to (256,2), KEEP b2-in-LDS, and
// re-apply the R13 chain split (now unconfounded: weights+bias in LDS freed
// 144 regs, so clA/clB + olA/olB (+32 regs) fit without spill).
// L2/L3 lo-chains go 8-deep -> two independent 4-deep; attacks the ~900
// cyc/iter of exposed MFMA dependency latency at 2 waves/SIMD.
//
// Split math (verified R5..R14, absmax 0.0039 = fp32 class):
//   a = hi + lo*2^-12; hi = RTZ_f16(a), lo = RTZ_f16((a-hi)*4096).
//   res = acc_hh + (acc_hl + acc_lh)*2^-12  (lo*lo dropped ~2^-24).
// L1 bias folded into k=7 slot (B k7 = 1.0 g0 lanes, A k7 = split(b1)).
//
// v_mfma_f32_32x32x16_f16 layouts (verified R5..R14):
//   A: row=lane&31, k=8*(lane>>5)+j ; B: col=lane&31, k=8*(lane>>5)+j
//   D: col=lane&31, row=(i&3)+8*(i>>2)+4*(lane>>5)
// sigma relabeling: packed D word (ct,m) == B-frag kb=2ct+(m>>2), w=m&3;
// consumer weight columns pre-permuted by sigma_inv at LDS-stage time.
//
// LDS: 28 weight frag slots (half8, p*64+lane) + b2 C-init table (64 f32).

typedef _Float16 half8  __attribute__((ext_vector_type(8)));
typedef __fp16   fp16x2 __attribute__((ext_vector_type(2)));
typedef float    floatx16 __attribute__((ext_vector_type(16)));
typedef unsigned int uint2v __attribute__((ext_vector_type(2)));

#define MFMA32(a, b, c) __builtin_amdgcn_mfma_f32_32x32x16_f16((a), (b), (c), 0, 0, 0)
#define LO_SCALE 2.44140625e-4f  /* 2^-12 */

union PairU { fp16x2 h; unsigned int u; };
union FragU { unsigned int w[4]; half8 h; };

static __device__ inline void split_pack2(float v0, float v1,
                                          unsigned int& hw, unsigned int& lw) {
    PairU hp, lp;
    hp.h = __builtin_amdgcn_cvt_pkrtz(v0, v1);          // 1 instr, RTZ
    float f0 = (float)hp.h[0], f1 = (float)hp.h[1];
    lp.h = __builtin_amdgcn_cvt_pkrtz((v0 - f0) * 4096.0f,
                                      (v1 - f1) * 4096.0f);
    hw = hp.u; lw = lp.u;
}

// B k-slot -> producer's natural output-neuron position (see R10 header).
static __device__ inline int sigma_inv(int k) {
    int ci = k >> 5, r = k & 31;
    int m  = 4 * ((r >> 4) & 1) + ((r >> 1) & 3);
    int i  = 2 * m + (r & 1);
    int gD = (r >> 3) & 1;
    return 32 * ci + (i & 3) + 8 * (i >> 2) + 4 * gD;
}

// 2x2 half-block transpose (quat epilogue only)
static __device__ inline void swap32(unsigned int a, unsigned int b,
                                     unsigned int& lo, unsigned int& hi) {
    uint2v r = __builtin_amdgcn_permlane32_swap(a, b, false, false);
    lo = r[0]; hi = r[1];
}

__global__ __launch_bounds__(256, 2) void pose_mlp_mfma_p(
    const float* __restrict__ x,
    const float* __restrict__ W1, const float* __restrict__ b1,
    const float* __restrict__ W2, const float* __restrict__ b2,
    const float* __restrict__ W3, const float* __restrict__ b3,
    float* __restrict__ out, int nrows)
{
    const int tid  = threadIdx.x;
    const int lane = tid & 63;
    const int wv   = tid >> 6;
    const int g    = lane >> 5;   // lane half (k-group / row-group)
    const int n5   = lane & 31;   // neuron row (A) / batch col (B/D)

    __shared__ half8 ldsW[28 * 64];   // 28 KB pre-split weight fragments
    __shared__ float b2lds[64];       // b2 C-init table, crow-permuted

    // ---- stage b2 table (threads 0..63) ----
    if (tid < 64) {
        const int gg = tid >> 5, ct = (tid >> 4) & 1, i = tid & 15;
        b2lds[tid] = b2[ct * 32 + (i & 3) + 8 * (i >> 2) + 4 * gg];
    }

    // ---- stage weight fragments (4 waves cooperatively, own lane each) ----
    for (int p = wv; p < 14; p += 4) {
        FragU H, L;
        if (p < 2) {                       // W1 pair, ct = p
            const int ct = p;
#pragma unroll
            for (int m = 0; m < 4; ++m) {
                int k0 = 2 * m, k1 = 2 * m + 1;
                float a0 = (g == 0) ? W1[(ct * 32 + n5) * 7 + k0] : 0.0f;
                float a1 = (g == 0) ? ((k1 < 7) ? W1[(ct * 32 + n5) * 7 + k1]
                                                : b1[ct * 32 + n5]) : 0.0f;
                split_pack2(a0, a1, H.w[m], L.w[m]);
            }
        } else if (p < 10) {               // W2 pair, q = p-2 -> (ct, kb)
            const int q = p - 2, ct = q >> 2, kb = q & 3;
            const float* wrow = W2 + (ct * 32 + n5) * 64;
#pragma unroll
            for (int m = 0; m < 4; ++m) {
                int k0 = kb * 16 + g * 8 + 2 * m;
                split_pack2(wrow[sigma_inv(k0)], wrow[sigma_inv(k0 + 1)],
                            H.w[m], L.w[m]);
            }
        } else {                           // W3 pair, kb = p-10
            const int kb = p - 10;
            const bool nv = (n5 < 7);
#pragma unroll
            for (int m = 0; m < 4; ++m) {
                int k0 = kb * 16 + g * 8 + 2 * m;
                float a0 = nv ? W3[n5 * 64 + sigma_inv(k0)]     : 0.0f;
                float a1 = nv ? W3[n5 * 64 + sigma_inv(k0 + 1)] : 0.0f;
                split_pack2(a0, a1, H.w[m], L.w[m]);
            }
        }
        ldsW[p * 64 + lane]        = H.h;
        ldsW[(14 + p) * 64 + lane] = L.h;
    }

    // loop-invariant accumulator C operand (zeros)
    floatx16 zero16;
#pragma unroll
    for (int i = 0; i < 16; ++i) zero16[i] = 0.0f;
    float b3t[4];
#pragma unroll
    for (int i = 0; i < 4; ++i)
        b3t[i] = g ? ((i < 3) ? b3[4 + i] : 0.0f) : b3[i];
    const float x7 = (g == 0) ? 1.0f : 0.0f;

    __syncthreads();   // weights + b2 table visible to all waves

    // ---------------- main loop: ITERS x 128 rows/block ----------------
    const int ITERS = 16;
    const int blk0 = blockIdx.x * (ITERS * 128);

    float xv[7] = {0.f,0.f,0.f,0.f,0.f,0.f,0.f};  // stays 0 in g1 lanes
    {
        int r = blk0 + wv * 32 + n5;
        if (g == 0 && r < nrows) {
            const float* xr = x + (size_t)r * 7;
#pragma unroll
            for (int j = 0; j < 7; ++j) xv[j] = xr[j];
        }
    }

    for (int it = 0; it < ITERS; ++it) {
        const int r0 = blk0 + it * 128 + wv * 32;

        // ---- X B-frag ----
        FragU xH, xL;
        split_pack2(xv[0], xv[1], xH.w[0], xL.w[0]);
        split_pack2(xv[2], xv[3], xH.w[1], xL.w[1]);
        split_pack2(xv[4], xv[5], xH.w[2], xL.w[2]);
        split_pack2(xv[6], x7,    xH.w[3], xL.w[3]);

        if (it < ITERS - 1) {
            int r = r0 + 128 + n5;
            if (g == 0 && r < nrows) {
                const float* xr = x + (size_t)r * 7;
#pragma unroll
                for (int j = 0; j < 7; ++j) xv[j] = xr[j];
            }
        }

        // ---- Layer 1: h1^T ; pack DIRECTLY into L2 B-frags (sigma) ----
        FragU AH[4], AL[4];
#pragma unroll
        for (int ct = 0; ct < 2; ++ct) {
            half8 wh = ldsW[ct * 64 + lane];
            half8 wl = ldsW[(14 + ct) * 64 + lane];
            floatx16 ah  = MFMA32(wh, xH.h, zero16);
            floatx16 alA = MFMA32(wh, xL.h, zero16);
            floatx16 alB = MFMA32(wl, xH.h, zero16);
#pragma unroll
            for (int m = 0; m < 8; ++m) {
                float v0 = fmaxf(fmaf(alA[2*m],   LO_SCALE,
                                 fmaf(alB[2*m],   LO_SCALE, ah[2*m])),   0.0f);
                float v1 = fmaxf(fmaf(alA[2*m+1], LO_SCALE,
                                 fmaf(alB[2*m+1], LO_SCALE, ah[2*m+1])), 0.0f);
                const int kb = 2 * ct + (m >> 2), w = m & 3;
                split_pack2(v0, v1, AH[kb].w[w], AL[kb].w[w]);
            }
        }

        // ---- Layer 2: h2^T ; 3 independent chains (ch 4-deep, clA/clB 4) ----
        FragU BH[4], BL[4];
#pragma unroll
        for (int ct = 0; ct < 2; ++ct) {
            floatx16 cinit = *(const floatx16*)&b2lds[(g * 2 + ct) * 16];
            floatx16 ch, clA, clB;
#pragma unroll
            for (int kb = 0; kb < 4; ++kb) {
                half8 wh = ldsW[(2 + ct * 4 + kb) * 64 + lane];
                half8 wl = ldsW[(16 + ct * 4 + kb) * 64 + lane];
                if (kb == 0) {
                    ch  = MFMA32(wh, AH[0].h, cinit);
                    clA = MFMA32(wh, AL[0].h, zero16);
                    clB = MFMA32(wl, AH[0].h, zero16);
                } else {
                    ch  = MFMA32(wh, AH[kb].h, ch);
                    clA = MFMA32(wh, AL[kb].h, clA);
                    clB = MFMA32(wl, AH[kb].h, clB);
                }
            }
#pragma unroll
            for (int m = 0; m < 8; ++m) {
                float v0 = fmaxf(fmaf(clA[2*m],   LO_SCALE,
                                 fmaf(clB[2*m],   LO_SCALE, ch[2*m])),   0.0f);
                float v1 = fmaxf(fmaf(clA[2*m+1], LO_SCALE,
                                 fmaf(clB[2*m+1], LO_SCALE, ch[2*m+1])), 0.0f);
                const int kb = 2 * ct + (m >> 2), w = m & 3;
                split_pack2(v0, v1, BH[kb].w[w], BL[kb].w[w]);
            }
        }

        // ---- Layer 3: 3 independent chains + quat epilogue ----
        {
            floatx16 oh, olA, olB;
#pragma unroll
            for (int kb = 0; kb < 4; ++kb) {
                half8 wh = ldsW[(10 + kb) * 64 + lane];
                half8 wl = ldsW[(24 + kb) * 64 + lane];
                if (kb == 0) {
                    oh  = MFMA32(wh, BH[0].h, zero16);
                    olA = MFMA32(wh, BL[0].h, zero16);
                    olB = MFMA32(wl, BH[0].h, zero16);
                } else {
                    oh  = MFMA32(wh, BH[kb].h, oh);
                    olA = MFMA32(wh, BL[kb].h, olA);
                    olB = MFMA32(wl, BH[kb].h, olB);
                }
            }
            float c0 = fmaf(olA[0], LO_SCALE, fmaf(olB[0], LO_SCALE, oh[0])) + b3t[0];
            float c1 = fmaf(olA[1], LO_SCALE, fmaf(olB[1], LO_SCALE, oh[1])) + b3t[1];
            float c2 = fmaf(olA[2], LO_SCALE, fmaf(olB[2], LO_SCALE, oh[2])) + b3t[2];
            float c3 = fmaf(olA[3], LO_SCALE, fmaf(olB[3], LO_SCALE, oh[3])) + b3t[3];

            float p = g ? fmaf(c2, c2, fmaf(c1, c1, c0 * c0)) : c3 * c3;
            unsigned int plo, phi;
            swap32(__float_as_uint(p), __float_as_uint(p), plo, phi);
            float other = __uint_as_float(g ? plo : phi);
            float s = p + other;
            float rn = 1.0f / sqrtf(s);

            int r = r0 + n5;
            if (r < nrows) {
                float* orow = out + (size_t)r * 7;
                if (g == 0) {
                    orow[0] = c0; orow[1] = c1; orow[2] = c2; orow[3] = c3 * rn;
                } else {
                    orow[4] = c0 * rn; orow[5] = c1 * rn; orow[6] = c2 * rn;
                }
            }
        }
    }
}

extern "C" void kernel_launch(void* const* d_in, const int* in_sizes, int n_in,
                              void* d_out, int out_size, void* d_ws, size_t ws_size,
                              hipStream_t stream)
{
    const float* x  = (const float*)d_in[0];
    const float* W1 = (const float*)d_in[1];
    const float* b1 = (const float*)d_in[2];
    const float* W2 = (const float*)d_in[3];
    const float* b2 = (const float*)d_in[4];
    const float* W3 = (const float*)d_in[5];
    const float* b3 = (const float*)d_in[6];
    float* out = (float*)d_out;

    const int nrows = in_sizes[0] / 7;
    const int rows_per_block = 16 * 128;  // ITERS * 128
    const int grid = (nrows + rows_per_block - 1) / rows_per_block;
    pose_mlp_mfma_p<<<grid, 256, 0, stream>>>(x, W1, b1, W2, b2, W3, b3, out, nrows);
}

// Round 21
// 96.612 us; speedup vs baseline: 2.6677x; 1.0639x over previous
//
#include <hip/hip_runtime.h>
#include <math.h>

// PoseMLP, transposed split-f16 MFMA, R21 = R17 resubmit x4 (container infra
// unresponsive four rounds running; kernel still unmeasured).
// R16 post-mortem: chain-split (+32 acc regs) re-spilled (WRITE 59k->68k);
// reverted. Model: R14 does 28 ds_read_b128/iter = 28.7KB/iter/wave;
// at 8 waves/CU and ~2045cyc/iter that is ~112 B/cyc vs 128 B/cyc LDS peak
// -> R14 is ~88% LDS-BW-bound. Fix: move the 8 W2-H frags into persistent
// REGISTERS (+32) -- read-only MFMA A-operands live in AGPRs without
// accvgpr churn (unlike accumulators, the R16 failure) -- paid for by b2
// staying in LDS (-32, bias2v eliminated). LDS reads 28 -> 22/iter.
// Accumulator chaining = R14 exactly (best known, 94us).
//
// Split math (verified R5..R16, absmax 0.0039 = fp32 class):
//   a = hi + lo*2^-12; hi = RTZ_f16(a), lo = RTZ_f16((a-hi)*4096).
//   res = acc_hh + (acc_hl + acc_lh)*2^-12  (lo*lo dropped ~2^-24).
// L1 bias folded into k=7 slot (B k7 = 1.0 g0 lanes, A k7 = split(b1)).
//
// v_mfma_f32_32x32x16_f16 layouts (verified R5..R16):
//   A: row=lane&31, k=8*(lane>>5)+j ; B: col=lane&31, k=8*(lane>>5)+j
//   D: col=lane&31, row=(i&3)+8*(i>>2)+4*(lane>>5)
// sigma relabeling: packed D word (ct,m) == B-frag kb=2ct+(m>>2), w=m&3;
// consumer weight columns pre-permuted by sigma_inv at LDS-stage time.
//
// LDS: 28 weight frag slots (half8, p*64+lane) + b2 C-init table (64 f32).

typedef _Float16 half8  __attribute__((ext_vector_type(8)));
typedef __fp16   fp16x2 __attribute__((ext_vector_type(2)));
typedef float    floatx16 __attribute__((ext_vector_type(16)));
typedef unsigned int uint2v __attribute__((ext_vector_type(2)));

#define MFMA32(a, b, c) __builtin_amdgcn_mfma_f32_32x32x16_f16((a), (b), (c), 0, 0, 0)
#define LO_SCALE 2.44140625e-4f  /* 2^-12 */

union PairU { fp16x2 h; unsigned int u; };
union FragU { unsigned int w[4]; half8 h; };

static __device__ inline void split_pack2(float v0, float v1,
                                          unsigned int& hw, unsigned int& lw) {
    PairU hp, lp;
    hp.h = __builtin_amdgcn_cvt_pkrtz(v0, v1);          // 1 instr, RTZ
    float f0 = (float)hp.h[0], f1 = (float)hp.h[1];
    lp.h = __builtin_amdgcn_cvt_pkrtz((v0 - f0) * 4096.0f,
                                      (v1 - f1) * 4096.0f);
    hw = hp.u; lw = lp.u;
}

// B k-slot -> producer's natural output-neuron position (see R10 header).
static __device__ inline int sigma_inv(int k) {
    int ci = k >> 5, r = k & 31;
    int m  = 4 * ((r >> 4) & 1) + ((r >> 1) & 3);
    int i  = 2 * m + (r & 1);
    int gD = (r >> 3) & 1;
    return 32 * ci + (i & 3) + 8 * (i >> 2) + 4 * gD;
}

// 2x2 half-block transpose (quat epilogue only)
static __device__ inline void swap32(unsigned int a, unsigned int b,
                                     unsigned int& lo, unsigned int& hi) {
    uint2v r = __builtin_amdgcn_permlane32_swap(a, b, false, false);
    lo = r[0]; hi = r[1];
}

__global__ __launch_bounds__(256, 2) void pose_mlp_mfma_r(
    const float* __restrict__ x,
    const float* __restrict__ W1, const float* __restrict__ b1,
    const float* __restrict__ W2, const float* __restrict__ b2,
    const float* __restrict__ W3, const float* __restrict__ b3,
    float* __restrict__ out, int nrows)
{
    const int tid  = threadIdx.x;
    const int lane = tid & 63;
    const int wv   = tid >> 6;
    const int g    = lane >> 5;   // lane half (k-group / row-group)
    const int n5   = lane & 31;   // neuron row (A) / batch col (B/D)

    __shared__ half8 ldsW[28 * 64];   // 28 KB pre-split weight fragments
    __shared__ float b2lds[64];       // b2 C-init table, crow-permuted

    // ---- stage b2 table (threads 0..63) ----
    if (tid < 64) {
        const int gg = tid >> 5, ct = (tid >> 4) & 1, i = tid & 15;
        b2lds[tid] = b2[ct * 32 + (i & 3) + 8 * (i >> 2) + 4 * gg];
    }

    // ---- stage weight fragments (4 waves cooperatively, own lane each) ----
    for (int p = wv; p < 14; p += 4) {
        FragU H, L;
        if (p < 2) {                       // W1 pair, ct = p
            const int ct = p;
#pragma unroll
            for (int m = 0; m < 4; ++m) {
                int k0 = 2 * m, k1 = 2 * m + 1;
                float a0 = (g == 0) ? W1[(ct * 32 + n5) * 7 + k0] : 0.0f;
                float a1 = (g == 0) ? ((k1 < 7) ? W1[(ct * 32 + n5) * 7 + k1]
                                                : b1[ct * 32 + n5]) : 0.0f;
                split_pack2(a0, a1, H.w[m], L.w[m]);
            }
        } else if (p < 10) {               // W2 pair, q = p-2 -> (ct, kb)
            const int q = p - 2, ct = q >> 2, kb = q & 3;
            const float* wrow = W2 + (ct * 32 + n5) * 64;
#pragma unroll
            for (int m = 0; m < 4; ++m) {
                int k0 = kb * 16 + g * 8 + 2 * m;
                split_pack2(wrow[sigma_inv(k0)], wrow[sigma_inv(k0 + 1)],
                            H.w[m], L.w[m]);
            }
        } else {                           // W3 pair, kb = p-10
            const int kb = p - 10;
            const bool nv = (n5 < 7);
#pragma unroll
            for (int m = 0; m < 4; ++m) {
                int k0 = kb * 16 + g * 8 + 2 * m;
                float a0 = nv ? W3[n5 * 64 + sigma_inv(k0)]     : 0.0f;
                float a1 = nv ? W3[n5 * 64 + sigma_inv(k0 + 1)] : 0.0f;
                split_pack2(a0, a1, H.w[m], L.w[m]);
            }
        }
        ldsW[p * 64 + lane]        = H.h;
        ldsW[(14 + p) * 64 + lane] = L.h;
    }

    // loop-invariant accumulator C operand (zeros)
    floatx16 zero16;
#pragma unroll
    for (int i = 0; i < 16; ++i) zero16[i] = 0.0f;
    float b3t[4];
#pragma unroll
    for (int i = 0; i < 4; ++i)
        b3t[i] = g ? ((i < 3) ? b3[4 + i] : 0.0f) : b3[i];
    const float x7 = (g == 0) ? 1.0f : 0.0f;

    __syncthreads();   // weights + b2 table visible to all waves

    // ---- hoist W2-H frags into persistent registers (read-only MFMA A
    // operands -> AGPR-resident without accvgpr churn). LDS 28->20 reads/iter.
    half8 w2hreg[2][4];
#pragma unroll
    for (int ct = 0; ct < 2; ++ct)
#pragma unroll
        for (int kb = 0; kb < 4; ++kb)
            w2hreg[ct][kb] = ldsW[(2 + ct * 4 + kb) * 64 + lane];

    // ---------------- main loop: ITERS x 128 rows/block ----------------
    const int ITERS = 16;
    const int blk0 = blockIdx.x * (ITERS * 128);

    float xv[7] = {0.f,0.f,0.f,0.f,0.f,0.f,0.f};  // stays 0 in g1 lanes
    {
        int r = blk0 + wv * 32 + n5;
        if (g == 0 && r < nrows) {
            const float* xr = x + (size_t)r * 7;
#pragma unroll
            for (int j = 0; j < 7; ++j) xv[j] = xr[j];
        }
    }

    for (int it = 0; it < ITERS; ++it) {
        const int r0 = blk0 + it * 128 + wv * 32;

        // ---- X B-frag ----
        FragU xH, xL;
        split_pack2(xv[0], xv[1], xH.w[0], xL.w[0]);
        split_pack2(xv[2], xv[3], xH.w[1], xL.w[1]);
        split_pack2(xv[4], xv[5], xH.w[2], xL.w[2]);
        split_pack2(xv[6], x7,    xH.w[3], xL.w[3]);

        if (it < ITERS - 1) {
            int r = r0 + 128 + n5;
            if (g == 0 && r < nrows) {
                const float* xr = x + (size_t)r * 7;
#pragma unroll
                for (int j = 0; j < 7; ++j) xv[j] = xr[j];
            }
        }

        // ---- Layer 1: h1^T ; pack DIRECTLY into L2 B-frags (sigma) ----
        FragU AH[4], AL[4];
#pragma unroll
        for (int ct = 0; ct < 2; ++ct) {
            half8 wh = ldsW[ct * 64 + lane];
            half8 wl = ldsW[(14 + ct) * 64 + lane];
            floatx16 ah = MFMA32(wh, xH.h, zero16);
            floatx16 al = MFMA32(wh, xL.h, zero16);
            al = MFMA32(wl, xH.h, al);
#pragma unroll
            for (int m = 0; m < 8; ++m) {
                float v0 = fmaxf(fmaf(al[2*m],   LO_SCALE, ah[2*m]),   0.0f);
                float v1 = fmaxf(fmaf(al[2*m+1], LO_SCALE, ah[2*m+1]), 0.0f);
                const int kb = 2 * ct + (m >> 2), w = m & 3;
                split_pack2(v0, v1, AH[kb].w[w], AL[kb].w[w]);
            }
        }

        // ---- Layer 2: h2^T ; W2-H from regs, W2-L from LDS ----
        FragU BH[4], BL[4];
#pragma unroll
        for (int ct = 0; ct < 2; ++ct) {
            floatx16 cinit = *(const floatx16*)&b2lds[(g * 2 + ct) * 16];
            floatx16 ch, cl;
#pragma unroll
            for (int kb = 0; kb < 4; ++kb) {
                half8 wh = w2hreg[ct][kb];
                half8 wl = ldsW[(16 + ct * 4 + kb) * 64 + lane];
                if (kb == 0) {
                    ch = MFMA32(wh, AH[0].h, cinit);
                    cl = MFMA32(wh, AL[0].h, zero16);
                    cl = MFMA32(wl, AH[0].h, cl);
                } else {
                    ch = MFMA32(wh, AH[kb].h, ch);
                    cl = MFMA32(wh, AL[kb].h, cl);
                    cl = MFMA32(wl, AH[kb].h, cl);
                }
            }
#pragma unroll
            for (int m = 0; m < 8; ++m) {
                float v0 = fmaxf(fmaf(cl[2*m],   LO_SCALE, ch[2*m]),   0.0f);
                float v1 = fmaxf(fmaf(cl[2*m+1], LO_SCALE, ch[2*m+1]), 0.0f);
                const int kb = 2 * ct + (m >> 2), w = m & 3;
                split_pack2(v0, v1, BH[kb].w[w], BL[kb].w[w]);
            }
        }

        // ---- Layer 3: o^T rows 0..6 + quat epilogue ----
        {
            floatx16 oh, ol;
#pragma unroll
            for (int kb = 0; kb < 4; ++kb) {
                half8 wh = ldsW[(10 + kb) * 64 + lane];
                half8 wl = ldsW[(24 + kb) * 64 + lane];
                if (kb == 0) {
                    oh = MFMA32(wh, BH[0].h, zero16);
                    ol = MFMA32(wh, BL[0].h, zero16);
                    ol = MFMA32(wl, BH[0].h, ol);
                } else {
                    oh = MFMA32(wh, BH[kb].h, oh);
                    ol = MFMA32(wh, BL[kb].h, ol);
                    ol = MFMA32(wl, BH[kb].h, ol);
                }
            }
            float c0 = fmaf(ol[0], LO_SCALE, oh[0]) + b3t[0];
            float c1 = fmaf(ol[1], LO_SCALE, oh[1]) + b3t[1];
            float c2 = fmaf(ol[2], LO_SCALE, oh[2]) + b3t[2];
            float c3 = fmaf(ol[3], LO_SCALE, oh[3]) + b3t[3];

            float p = g ? fmaf(c2, c2, fmaf(c1, c1, c0 * c0)) : c3 * c3;
            unsigned int plo, phi;
            swap32(__float_as_uint(p), __float_as_uint(p), plo, phi);
            float other = __uint_as_float(g ? plo : phi);
            float s = p + other;
            float rn = 1.0f / sqrtf(s);

            int r = r0 + n5;
            if (r < nrows) {
                float* orow = out + (size_t)r * 7;
                if (g == 0) {
                    orow[0] = c0; orow[1] = c1; orow[2] = c2; orow[3] = c3 * rn;
                } else {
                    orow[4] = c0 * rn; orow[5] = c1 * rn; orow[6] = c2 * rn;
                }
            }
        }
    }
}

extern "C" void kernel_launch(void* const* d_in, const int* in_sizes, int n_in,
                              void* d_out, int out_size, void* d_ws, size_t ws_size,
                              hipStream_t stream)
{
    const float* x  = (const float*)d_in[0];
    const float* W1 = (const float*)d_in[1];
    const float* b1 = (const float*)d_in[2];
    const float* W2 = (const float*)d_in[3];
    const float* b2 = (const float*)d_in[4];
    const float* W3 = (const float*)d_in[5];
    const float* b3 = (const float*)d_in[6];
    float* out = (float*)d_out;

    const int nrows = in_sizes[0] / 7;
    const int rows_per_block = 16 * 128;  // ITERS * 128
    const int grid = (nrows + rows_per_block - 1) / rows_per_block;
    pose_mlp_mfma_r<<<grid, 256, 0, stream>>>(x, W1, b1, W2, b2, W3, b3, out, nrows);
}

// Round 22
// 93.523 us; speedup vs baseline: 2.7558x; 1.0330x over previous
//
#include <hip/hip_runtime.h>
#include <math.h>

// PoseMLP, transposed split-f16 MFMA — FINAL (R14 verbatim, best measured:
// 94.0 us timed, absmax 0.0039, 3.3x over fp32-VALU baseline 307 us).
//
// Session summary of measured structure:
//  - fp32 1-thread/row baseline: 307 us (VALU-bound, 79% VALUBusy).
//  - split-f16 MFMA (3-pass hi/lo, fp32-class error): 181 -> 115 (register-
//    resident transposed) -> 100.7 (permlane32_swap) -> 94.0 (weights in LDS).
//  - Plateau: wall = dependency latency at 2 waves/SIMD, pinned by ~250-reg
//    unified (VGPR+AGPR) footprint. Measured failures to break it: 1-wave
//    blocks (-34%), chain-split (spill), launch_bounds(256,3) (VGPR=84,
//    FETCH 29k->548k, -174%), W2-H reg hoist (-3%), bias-to-LDS (neutral).
//    No pipe saturated (VALU 58%, LDS 22%, HBM 10%, MFMA <10% issue).
//
// Math: a = hi + lo*2^-12 (hi=RTZ_f16(a), lo=RTZ_f16((a-hi)*4096));
//   res = acc_hh + (acc_hl + acc_lh)*2^-12; lo*lo dropped (~2^-24).
//   L1 bias in k=7 slot (B k7 = 1.0 g0 lanes, A k7 = split(b1)).
// v_mfma_f32_32x32x16_f16 layouts (verified R5..R21):
//   A: row=lane&31, k=8*(lane>>5)+j ; B: col=lane&31, k=8*(lane>>5)+j
//   D: col=lane&31, row=(i&3)+8*(i>>2)+4*(lane>>5)
// sigma relabeling: packed D word (ct,m) == B-frag kb=2ct+(m>>2), w=m&3;
// consumer weight columns pre-permuted by sigma_inv at LDS-stage time ->
// zero-instruction layer transitions.

typedef _Float16 half8  __attribute__((ext_vector_type(8)));
typedef __fp16   fp16x2 __attribute__((ext_vector_type(2)));
typedef float    floatx16 __attribute__((ext_vector_type(16)));
typedef unsigned int uint2v __attribute__((ext_vector_type(2)));

#define MFMA32(a, b, c) __builtin_amdgcn_mfma_f32_32x32x16_f16((a), (b), (c), 0, 0, 0)
#define LO_SCALE 2.44140625e-4f  /* 2^-12 */

union PairU { fp16x2 h; unsigned int u; };
union FragU { unsigned int w[4]; half8 h; };

static __device__ inline void split_pack2(float v0, float v1,
                                          unsigned int& hw, unsigned int& lw) {
    PairU hp, lp;
    hp.h = __builtin_amdgcn_cvt_pkrtz(v0, v1);          // 1 instr, RTZ
    float f0 = (float)hp.h[0], f1 = (float)hp.h[1];
    lp.h = __builtin_amdgcn_cvt_pkrtz((v0 - f0) * 4096.0f,
                                      (v1 - f1) * 4096.0f);
    hw = hp.u; lw = lp.u;
}

// B k-slot -> producer's natural output-neuron position.
static __device__ inline int sigma_inv(int k) {
    int ci = k >> 5, r = k & 31;
    int m  = 4 * ((r >> 4) & 1) + ((r >> 1) & 3);
    int i  = 2 * m + (r & 1);
    int gD = (r >> 3) & 1;
    return 32 * ci + (i & 3) + 8 * (i >> 2) + 4 * gD;
}

// 2x2 half-block transpose (quat epilogue only)
static __device__ inline void swap32(unsigned int a, unsigned int b,
                                     unsigned int& lo, unsigned int& hi) {
    uint2v r = __builtin_amdgcn_permlane32_swap(a, b, false, false);
    lo = r[0]; hi = r[1];
}

__global__ __launch_bounds__(256, 2) void pose_mlp_mfma_l(
    const float* __restrict__ x,
    const float* __restrict__ W1, const float* __restrict__ b1,
    const float* __restrict__ W2, const float* __restrict__ b2,
    const float* __restrict__ W3, const float* __restrict__ b3,
    float* __restrict__ out, int nrows)
{
    const int tid  = threadIdx.x;
    const int lane = tid & 63;
    const int wv   = tid >> 6;
    const int g    = lane >> 5;   // lane half (k-group / row-group)
    const int n5   = lane & 31;   // neuron row (A) / batch col (B/D)

    __shared__ half8 ldsW[28 * 64];   // 28 KB of pre-split weight fragments

    // ---- stage weight fragments (4 waves cooperatively, own lane each) ----
    for (int p = wv; p < 14; p += 4) {
        FragU H, L;
        if (p < 2) {                       // W1 pair, ct = p
            const int ct = p;
#pragma unroll
            for (int m = 0; m < 4; ++m) {
                int k0 = 2 * m, k1 = 2 * m + 1;
                float a0 = (g == 0) ? W1[(ct * 32 + n5) * 7 + k0] : 0.0f;
                float a1 = (g == 0) ? ((k1 < 7) ? W1[(ct * 32 + n5) * 7 + k1]
                                                : b1[ct * 32 + n5]) : 0.0f;
                split_pack2(a0, a1, H.w[m], L.w[m]);
            }
        } else if (p < 10) {               // W2 pair, q = p-2 -> (ct, kb)
            const int q = p - 2, ct = q >> 2, kb = q & 3;
            const float* wrow = W2 + (ct * 32 + n5) * 64;
#pragma unroll
            for (int m = 0; m < 4; ++m) {
                int k0 = kb * 16 + g * 8 + 2 * m;
                split_pack2(wrow[sigma_inv(k0)], wrow[sigma_inv(k0 + 1)],
                            H.w[m], L.w[m]);
            }
        } else {                           // W3 pair, kb = p-10
            const int kb = p - 10;
            const bool nv = (n5 < 7);
#pragma unroll
            for (int m = 0; m < 4; ++m) {
                int k0 = kb * 16 + g * 8 + 2 * m;
                float a0 = nv ? W3[n5 * 64 + sigma_inv(k0)]     : 0.0f;
                float a1 = nv ? W3[n5 * 64 + sigma_inv(k0 + 1)] : 0.0f;
                split_pack2(a0, a1, H.w[m], L.w[m]);
            }
        }
        ldsW[p * 64 + lane]        = H.h;
        ldsW[(14 + p) * 64 + lane] = L.h;
    }

    // loop-invariant accumulator C operands
    floatx16 zero16;
#pragma unroll
    for (int i = 0; i < 16; ++i) zero16[i] = 0.0f;
    floatx16 bias2v[2];
#pragma unroll
    for (int ct = 0; ct < 2; ++ct)
#pragma unroll
        for (int i = 0; i < 16; ++i)
            bias2v[ct][i] = b2[ct * 32 + (i & 3) + 8 * (i >> 2) + 4 * g];
    float b3t[4];
#pragma unroll
    for (int i = 0; i < 4; ++i)
        b3t[i] = g ? ((i < 3) ? b3[4 + i] : 0.0f) : b3[i];
    const float x7 = (g == 0) ? 1.0f : 0.0f;

    __syncthreads();   // weights visible to all waves

    // ---------------- main loop: ITERS x 128 rows/block ----------------
    const int ITERS = 16;
    const int blk0 = blockIdx.x * (ITERS * 128);

    float xv[7] = {0.f,0.f,0.f,0.f,0.f,0.f,0.f};  // stays 0 in g1 lanes
    {
        int r = blk0 + wv * 32 + n5;
        if (g == 0 && r < nrows) {
            const float* xr = x + (size_t)r * 7;
#pragma unroll
            for (int j = 0; j < 7; ++j) xv[j] = xr[j];
        }
    }

    for (int it = 0; it < ITERS; ++it) {
        const int r0 = blk0 + it * 128 + wv * 32;

        // ---- X B-frag ----
        FragU xH, xL;
        split_pack2(xv[0], xv[1], xH.w[0], xL.w[0]);
        split_pack2(xv[2], xv[3], xH.w[1], xL.w[1]);
        split_pack2(xv[4], xv[5], xH.w[2], xL.w[2]);
        split_pack2(xv[6], x7,    xH.w[3], xL.w[3]);

        if (it < ITERS - 1) {
            int r = r0 + 128 + n5;
            if (g == 0 && r < nrows) {
                const float* xr = x + (size_t)r * 7;
#pragma unroll
                for (int j = 0; j < 7; ++j) xv[j] = xr[j];
            }
        }

        // ---- Layer 1: h1^T ; pack DIRECTLY into L2 B-frags (sigma) ----
        FragU AH[4], AL[4];
#pragma unroll
        for (int ct = 0; ct < 2; ++ct) {
            half8 wh = ldsW[ct * 64 + lane];
            half8 wl = ldsW[(14 + ct) * 64 + lane];
            floatx16 ah = MFMA32(wh, xH.h, zero16);
            floatx16 al = MFMA32(wh, xL.h, zero16);
            al = MFMA32(wl, xH.h, al);
#pragma unroll
            for (int m = 0; m < 8; ++m) {
                float v0 = fmaxf(fmaf(al[2*m],   LO_SCALE, ah[2*m]),   0.0f);
                float v1 = fmaxf(fmaf(al[2*m+1], LO_SCALE, ah[2*m+1]), 0.0f);
                const int kb = 2 * ct + (m >> 2), w = m & 3;
                split_pack2(v0, v1, AH[kb].w[w], AL[kb].w[w]);
            }
        }

        // ---- Layer 2: h2^T ; pack into L3 B-frags (sigma) ----
        FragU BH[4], BL[4];
#pragma unroll
        for (int ct = 0; ct < 2; ++ct) {
            floatx16 ch, cl;
#pragma unroll
            for (int kb = 0; kb < 4; ++kb) {
                half8 wh = ldsW[(2 + ct * 4 + kb) * 64 + lane];
                half8 wl = ldsW[(16 + ct * 4 + kb) * 64 + lane];
                if (kb == 0) {
                    ch = MFMA32(wh, AH[0].h, bias2v[ct]);
                    cl = MFMA32(wh, AL[0].h, zero16);
                    cl = MFMA32(wl, AH[0].h, cl);
                } else {
                    ch = MFMA32(wh, AH[kb].h, ch);
                    cl = MFMA32(wh, AL[kb].h, cl);
                    cl = MFMA32(wl, AH[kb].h, cl);
                }
            }
#pragma unroll
            for (int m = 0; m < 8; ++m) {
                float v0 = fmaxf(fmaf(cl[2*m],   LO_SCALE, ch[2*m]),   0.0f);
                float v1 = fmaxf(fmaf(cl[2*m+1], LO_SCALE, ch[2*m+1]), 0.0f);
                const int kb = 2 * ct + (m >> 2), w = m & 3;
                split_pack2(v0, v1, BH[kb].w[w], BL[kb].w[w]);
            }
        }

        // ---- Layer 3: o^T rows 0..6 + quat epilogue ----
        {
            floatx16 oh, ol;
#pragma unroll
            for (int kb = 0; kb < 4; ++kb) {
                half8 wh = ldsW[(10 + kb) * 64 + lane];
                half8 wl = ldsW[(24 + kb) * 64 + lane];
                if (kb == 0) {
                    oh = MFMA32(wh, BH[0].h, zero16);
                    ol = MFMA32(wh, BL[0].h, zero16);
                    ol = MFMA32(wl, BH[0].h, ol);
                } else {
                    oh = MFMA32(wh, BH[kb].h, oh);
                    ol = MFMA32(wh, BL[kb].h, ol);
                    ol = MFMA32(wl, BH[kb].h, ol);
                }
            }
            float c0 = fmaf(ol[0], LO_SCALE, oh[0]) + b3t[0];
            float c1 = fmaf(ol[1], LO_SCALE, oh[1]) + b3t[1];
            float c2 = fmaf(ol[2], LO_SCALE, oh[2]) + b3t[2];
            float c3 = fmaf(ol[3], LO_SCALE, oh[3]) + b3t[3];

            float p = g ? fmaf(c2, c2, fmaf(c1, c1, c0 * c0)) : c3 * c3;
            unsigned int plo, phi;
            swap32(__float_as_uint(p), __float_as_uint(p), plo, phi);
            float other = __uint_as_float(g ? plo : phi);
            float s = p + other;
            float rn = 1.0f / sqrtf(s);

            int r = r0 + n5;
            if (r < nrows) {
                float* orow = out + (size_t)r * 7;
                if (g == 0) {
                    orow[0] = c0; orow[1] = c1; orow[2] = c2; orow[3] = c3 * rn;
                } else {
                    orow[4] = c0 * rn; orow[5] = c1 * rn; orow[6] = c2 * rn;
                }
            }
        }
    }
}

extern "C" void kernel_launch(void* const* d_in, const int* in_sizes, int n_in,
                              void* d_out, int out_size, void* d_ws, size_t ws_size,
                              hipStream_t stream)
{
    const float* x  = (const float*)d_in[0];
    const float* W1 = (const float*)d_in[1];
    const float* b1 = (const float*)d_in[2];
    const float* W2 = (const float*)d_in[3];
    const float* b2 = (const float*)d_in[4];
    const float* W3 = (const float*)d_in[5];
    const float* b3 = (const float*)d_in[6];
    float* out = (float*)d_out;

    const int nrows = in_sizes[0] / 7;
    const int rows_per_block = 16 * 128;  // ITERS * 128
    const int grid = (nrows + rows_per_block - 1) / rows_per_block;
    pose_mlp_mfma_l<<<grid, 256, 0, stream>>>(x, W1, b1, W2, b2, W3, b3, out, nrows);
}